// Round 3
// baseline (1074.648 us; speedup 1.0000x reference)
//
#include <hip/hip_runtime.h>
#include <stdint.h>

#define S_LEN 2048
#define DMODEL 4096
#define NHEAD 32
#define HDIM 128

typedef __attribute__((ext_vector_type(8))) short bf16x8;
typedef __attribute__((ext_vector_type(4))) float f32x4;

__device__ __forceinline__ unsigned short f2bf(float f) {
    union { float f; unsigned u; } v; v.f = f;
    unsigned u = v.u;
    unsigned r = (u + 0x7FFFu + ((u >> 16) & 1u)) >> 16;   // RNE
    return (unsigned short)r;
}
__device__ __forceinline__ float bf2f(unsigned short h) {
    union { unsigned u; float f; } v; v.u = ((unsigned)h) << 16;
    return v.f;
}

// ---------- elementwise f32 -> bf16 (4 per thread) ----------
__global__ void convert_x_kernel(const float* __restrict__ x,
                                 unsigned short* __restrict__ xb, int n4) {
    int t = blockIdx.x * blockDim.x + threadIdx.x;
    if (t >= n4) return;
    float4 v = ((const float4*)x)[t];
    ushort4 o;
    o.x = f2bf(v.x); o.y = f2bf(v.y); o.z = f2bf(v.z); o.w = f2bf(v.w);
    ((ushort4*)xb)[t] = o;
}

// ---------- transpose+convert weight: w[k][n] f32 -> wt[n][k] bf16 ----------
__global__ void convert_wt_kernel(const float* __restrict__ w,
                                  unsigned short* __restrict__ wt) {
    __shared__ unsigned short t[64][65];
    int n0 = blockIdx.x * 64, k0 = blockIdx.y * 64;
    for (int i = 0; i < 16; ++i) {
        int o = threadIdx.x + i * 256;
        int r = o >> 6, c = o & 63;
        t[r][c] = f2bf(w[(size_t)(k0 + r) * DMODEL + n0 + c]);
    }
    __syncthreads();
    for (int i = 0; i < 16; ++i) {
        int o = threadIdx.x + i * 256;
        int rr = o >> 6, kk = o & 63;
        wt[(size_t)(n0 + rr) * DMODEL + k0 + kk] = t[kk][rr];
    }
}

// ---------- GEMM: C[M,N] = A[M,K] * BT[N,K]^T, bf16 in, fp32 acc ----------
template<int STORE_MODE>
__global__ __launch_bounds__(256, 2)
void gemm_bt_kernel(const unsigned short* __restrict__ A,
                    const unsigned short* __restrict__ BT,
                    void* __restrict__ C, int M, int N, int K) {
    __shared__ __align__(16) unsigned short As[128 * 32];
    __shared__ __align__(16) unsigned short Bs[128 * 32];
    const int lane = threadIdx.x & 63;
    const int w = threadIdx.x >> 6;
    const int wm = w & 1, wn = w >> 1;
    const int m0 = blockIdx.y * 128, n0 = blockIdx.x * 128;

    f32x4 zero = {0.f, 0.f, 0.f, 0.f};
    f32x4 acc[4][4];
    for (int i = 0; i < 4; ++i)
        for (int j = 0; j < 4; ++j) acc[i][j] = zero;

    const int lr = lane >> 2;
    const int lc = lane & 3;
    const int q = lane >> 4, lm = lane & 15;

    for (int k0 = 0; k0 < K; k0 += 32) {
        __syncthreads();
        for (int i = 0; i < 2; ++i) {
            int rb = w * 32 + i * 16;
            int r = rb + lr;
            int gc = lc ^ ((r >> 1) & 3);
            const unsigned short* ga = A + (size_t)(m0 + r) * K + k0 + gc * 8;
            __builtin_amdgcn_global_load_lds(
                (__attribute__((address_space(1))) unsigned int*)ga,
                (__attribute__((address_space(3))) unsigned int*)(&As[rb * 32]), 16, 0, 0);
            const unsigned short* gb = BT + (size_t)(n0 + r) * K + k0 + gc * 8;
            __builtin_amdgcn_global_load_lds(
                (__attribute__((address_space(1))) unsigned int*)gb,
                (__attribute__((address_space(3))) unsigned int*)(&Bs[rb * 32]), 16, 0, 0);
        }
        __syncthreads();
        bf16x8 af[4], bf[4];
        for (int t = 0; t < 4; ++t) {
            int ra = wm * 64 + t * 16 + lm;
            af[t] = *(const bf16x8*)&As[ra * 32 + ((q ^ ((ra >> 1) & 3)) * 8)];
            int rb2 = wn * 64 + t * 16 + lm;
            bf[t] = *(const bf16x8*)&Bs[rb2 * 32 + ((q ^ ((rb2 >> 1) & 3)) * 8)];
        }
        for (int mi = 0; mi < 4; ++mi)
            for (int ni = 0; ni < 4; ++ni)
                acc[mi][ni] = __builtin_amdgcn_mfma_f32_16x16x32_bf16(
                    af[mi], bf[ni], acc[mi][ni], 0, 0, 0);
    }

    for (int mi = 0; mi < 4; ++mi) {
        int mbase = m0 + wm * 64 + mi * 16 + q * 4;
        for (int ni = 0; ni < 4; ++ni) {
            int n = n0 + wn * 64 + ni * 16 + lm;
            if (STORE_MODE == 0) {
                unsigned short* Cb = (unsigned short*)C;
                for (int r = 0; r < 4; ++r)
                    Cb[(size_t)(mbase + r) * N + n] = f2bf(acc[mi][ni][r]);
            } else if (STORE_MODE == 1) {
                unsigned short* Cb = (unsigned short*)C;
                ushort4 v;
                v.x = f2bf(acc[mi][ni][0]); v.y = f2bf(acc[mi][ni][1]);
                v.z = f2bf(acc[mi][ni][2]); v.w = f2bf(acc[mi][ni][3]);
                *(ushort4*)&Cb[(size_t)n * M + mbase] = v;
            } else {
                float* Cf = (float*)C;
                for (int r = 0; r < 4; ++r)
                    Cf[(size_t)(mbase + r) * N + n] = acc[mi][ni][r];
            }
        }
    }
}

// ---------- RoPE in-place on k only (q-rope is fused into attn) ----------
__global__ void rope_k_kernel(unsigned short* __restrict__ kb) {
    int t = blockIdx.x * blockDim.x + threadIdx.x;   // S*D/2 pairs
    if (t >= S_LEN * DMODEL / 2) return;
    int s = t >> 11;
    int p = t & 2047;
    int j = p & 63;
    float ang = (float)s * exp2f((float)j * -0.2076205059304602f);
    float sn, cs;
    sincosf(ang, &sn, &cs);
    size_t idx = (size_t)s * DMODEL + 2 * p;
    float b0 = bf2f(kb[idx]), b1 = bf2f(kb[idx + 1]);
    kb[idx]     = f2bf(b0 * cs - b1 * sn);
    kb[idx + 1] = f2bf(b0 * sn + b1 * cs);
}

// ---------- flash attention v3: barrier-free, direct global->register ----------
// 4 waves/block, each wave fully independent: 16 queries, one head.
// K/V fragments loaded straight into VGPRs in MFMA B-operand layout
// (8 contiguous shorts per lane). No K/V LDS, no __syncthreads.
// Software pipeline: V(c) issued before QK(c); K(c+1) issued after QK(c).
// Row-sum via ones-MFMA (kills the sum shfl chain); only 4-shfl max remains.
__global__ __launch_bounds__(256, 2)
void attn_kernel(const unsigned short* __restrict__ qb,   // raw q (no rope)
                 const unsigned short* __restrict__ kb,   // k with rope
                 const unsigned short* __restrict__ vt,   // v^T [h*hd+d][s]
                 unsigned short* __restrict__ ab) {
    __shared__ __align__(16) unsigned short Pb[4][16 * 72]; // per-wave P staging
    const int t = threadIdx.x;
    const int lane = t & 63;
    const int w = t >> 6;
    const int h = blockIdx.y;
    const int q0 = ((int)gridDim.x - 1 - (int)blockIdx.x) * 64;  // longest first
    const int qw = q0 + w * 16;
    const int q = lane >> 4, lm = lane & 15;

    // --- load q fragments, apply rope + 1/sqrt(hd) in-register (one-time) ---
    bf16x8 qf[4];
    {
        const int s = qw + lm;
        const unsigned short* gq = qb + (size_t)s * DMODEL + h * HDIM + q * 8;
        const float SC = 0.08838834764831845f;
#pragma unroll
        for (int kc = 0; kc < 4; ++kc) {
            bf16x8 raw = *(const bf16x8*)&gq[kc * 32];
            bf16x8 ov;
#pragma unroll
            for (int tt = 0; tt < 4; ++tt) {
                int p = kc * 16 + q * 4 + tt;
                float ang = (float)s * exp2f((float)p * -0.2076205059304602f);
                float sn, cs;
                sincosf(ang, &sn, &cs);
                float a0 = bf2f((unsigned short)raw[2 * tt]);
                float a1 = bf2f((unsigned short)raw[2 * tt + 1]);
                ov[2 * tt]     = (short)f2bf((a0 * cs - a1 * sn) * SC);
                ov[2 * tt + 1] = (short)f2bf((a0 * sn + a1 * cs) * SC);
            }
            qf[kc] = ov;
        }
    }

    // per-lane global bases
    const unsigned short* gK = kb + (size_t)lm * DMODEL + h * HDIM + q * 8;
    const unsigned short* gV = vt + (size_t)(h * HDIM + lm) * S_LEN + q * 8;

    f32x4 zero = {0.f, 0.f, 0.f, 0.f};
    f32x4 o[8];
#pragma unroll
    for (int i = 0; i < 8; ++i) o[i] = zero;
    f32x4 ls = zero;                       // row sums via ones-MFMA
    float mrow[4] = {-1e30f, -1e30f, -1e30f, -1e30f};

    bf16x8 ones;
#pragma unroll
    for (int i = 0; i < 8; ++i) ones[i] = (short)0x3F80;

    const int nch = q0 / 64 + 1;

    bf16x8 kf[16], vf[16];
    // preload K chunk 0: kf[ks*4+kc] = K[ks*16+lm][kc*32 + q*8 ..]
#pragma unroll
    for (int ks = 0; ks < 4; ++ks)
#pragma unroll
        for (int kc = 0; kc < 4; ++kc)
            kf[ks * 4 + kc] = *(const bf16x8*)&gK[(size_t)(ks * 16) * DMODEL + kc * 32];

    for (int c = 0; c < nch; ++c) {
        const int j0 = c * 64;
        // issue V(c): vf[nt*2+hf] = V^T[nt*16+lm][j0 + hf*32 + q*8 ..]
#pragma unroll
        for (int nt = 0; nt < 8; ++nt)
#pragma unroll
            for (int hf = 0; hf < 2; ++hf)
                vf[nt * 2 + hf] = *(const bf16x8*)&gV[(size_t)(nt * 16) * S_LEN + j0 + hf * 32];

        // QK^T
        f32x4 s[4];
#pragma unroll
        for (int ks = 0; ks < 4; ++ks) s[ks] = zero;
#pragma unroll
        for (int kc = 0; kc < 4; ++kc)
#pragma unroll
            for (int ks = 0; ks < 4; ++ks)
                s[ks] = __builtin_amdgcn_mfma_f32_16x16x32_bf16(qf[kc], kf[ks * 4 + kc], s[ks], 0, 0, 0);

        // prefetch K(c+1) — overlaps softmax + PV + next-iter V issue
        if (c + 1 < nch) {
            const size_t jn = (size_t)(j0 + 64);
#pragma unroll
            for (int ks = 0; ks < 4; ++ks)
#pragma unroll
                for (int kc = 0; kc < 4; ++kc)
                    kf[ks * 4 + kc] = *(const bf16x8*)&gK[(jn + ks * 16) * DMODEL + kc * 32];
        }

        // causal mask (only the diagonal chunk needs it)
        if (c == nch - 1) {
#pragma unroll
            for (int ks = 0; ks < 4; ++ks)
#pragma unroll
                for (int r = 0; r < 4; ++r)
                    if (j0 + ks * 16 + lm > qw + q * 4 + r) s[ks][r] = -1e30f;
        }

        // online softmax: max via 4 shfls (4-row ILP), sum via ones-MFMA later
        float al[4];
#pragma unroll
        for (int r = 0; r < 4; ++r) {
            float mx = fmaxf(fmaxf(s[0][r], s[1][r]), fmaxf(s[2][r], s[3][r]));
            mx = fmaxf(mx, __shfl_xor(mx, 1));
            mx = fmaxf(mx, __shfl_xor(mx, 2));
            mx = fmaxf(mx, __shfl_xor(mx, 4));
            mx = fmaxf(mx, __shfl_xor(mx, 8));
            float mn = fmaxf(mrow[r], mx);
            al[r] = __expf(mrow[r] - mn);
            mrow[r] = mn;
#pragma unroll
            for (int ks = 0; ks < 4; ++ks)
                Pb[w][(q * 4 + r) * 72 + ks * 16 + lm] = f2bf(__expf(s[ks][r] - mn));
        }
        // P: C-layout -> A-operand layout via per-wave LDS (in-wave DS ordering)
        bf16x8 pA0 = *(const bf16x8*)&Pb[w][lm * 72 + q * 8];
        bf16x8 pA1 = *(const bf16x8*)&Pb[w][lm * 72 + 32 + q * 8];

        // rescale and accumulate: o += P V, ls += P 1
        f32x4 lss = ls;
#pragma unroll
        for (int r = 0; r < 4; ++r) lss[r] *= al[r];
        lss = __builtin_amdgcn_mfma_f32_16x16x32_bf16(pA0, ones, lss, 0, 0, 0);
        ls = __builtin_amdgcn_mfma_f32_16x16x32_bf16(pA1, ones, lss, 0, 0, 0);
#pragma unroll
        for (int nt = 0; nt < 8; ++nt) {
            f32x4 oo = o[nt];
#pragma unroll
            for (int r = 0; r < 4; ++r) oo[r] *= al[r];
            oo = __builtin_amdgcn_mfma_f32_16x16x32_bf16(pA0, vf[nt * 2 + 0], oo, 0, 0, 0);
            o[nt] = __builtin_amdgcn_mfma_f32_16x16x32_bf16(pA1, vf[nt * 2 + 1], oo, 0, 0, 0);
        }
    }

    float inv[4];
#pragma unroll
    for (int r = 0; r < 4; ++r) inv[r] = 1.0f / ls[r];
#pragma unroll
    for (int nt = 0; nt < 8; ++nt) {
        int d = h * HDIM + lm + nt * 16;
#pragma unroll
        for (int r = 0; r < 4; ++r)
            ab[(size_t)(qw + q * 4 + r) * DMODEL + d] = f2bf(o[nt][r] * inv[r]);
    }
}

extern "C" void kernel_launch(void* const* d_in, const int* in_sizes, int n_in,
                              void* d_out, int out_size, void* d_ws, size_t ws_size,
                              hipStream_t stream) {
    const float* x  = (const float*)d_in[0];
    const float* wq = (const float*)d_in[1];
    const float* wk = (const float*)d_in[2];
    const float* wv = (const float*)d_in[3];
    const float* wo = (const float*)d_in[4];
    char* ws = (char*)d_ws;
    const size_t MB = 1024 * 1024;
    unsigned short* xb  = (unsigned short*)(ws + 0 * MB);
    unsigned short* qb  = (unsigned short*)(ws + 16 * MB);
    unsigned short* kb  = (unsigned short*)(ws + 32 * MB);
    unsigned short* vtb = (unsigned short*)(ws + 48 * MB);
    unsigned short* ab  = (unsigned short*)(ws + 64 * MB);
    unsigned short* wtb = (unsigned short*)(ws + 80 * MB);

    dim3 cg(64, 64);
    dim3 gg(32, 16);

    convert_x_kernel<<<(S_LEN * DMODEL / 4) / 256, 256, 0, stream>>>(x, xb, S_LEN * DMODEL / 4);

    convert_wt_kernel<<<cg, 256, 0, stream>>>(wq, wtb);
    gemm_bt_kernel<0><<<gg, 256, 0, stream>>>(xb, wtb, qb, S_LEN, DMODEL, DMODEL);
    convert_wt_kernel<<<cg, 256, 0, stream>>>(wk, wtb);
    gemm_bt_kernel<0><<<gg, 256, 0, stream>>>(xb, wtb, kb, S_LEN, DMODEL, DMODEL);
    convert_wt_kernel<<<cg, 256, 0, stream>>>(wv, wtb);
    gemm_bt_kernel<1><<<gg, 256, 0, stream>>>(xb, wtb, vtb, S_LEN, DMODEL, DMODEL);

    rope_k_kernel<<<(S_LEN * DMODEL / 2) / 256, 256, 0, stream>>>(kb);

    attn_kernel<<<dim3(S_LEN / 64, NHEAD), 256, 0, stream>>>(qb, kb, vtb, ab);

    convert_wt_kernel<<<cg, 256, 0, stream>>>(wo, wtb);
    gemm_bt_kernel<2><<<gg, 256, 0, stream>>>(ab, wtb, d_out, S_LEN, DMODEL, DMODEL);
}